// Round 10
// baseline (2957.624 us; speedup 1.0000x reference)
//
#include <hip/hip_runtime.h>
#include <hip/hip_bf16.h>
#include <stdint.h>

// ---------------------------------------------------------------------------
// BiLSTM classifier: V=50000 E=100 H=128 B=128 T=1024 C=2. f32 I/O.
// Round 10 = r9 + 16-wave lstm blocks (4 waves/SIMD) via r-split pairs:
//   waves (wv, wv+8) duplicate the MFMA chain (MFMA pipe has headroom) but
//   each does gate math / h-writes for only 2 of the 4 C-rows -> per-wave
//   trans halves, per-SIMD issue constant, 4 independent streams/SIMD hide
//   the ds_read->MFMA->exp2 dependency stalls that dominate r9 (~1000 cyc).
//   Kept-row arithmetic bit-identical to r9. Proj reworked for 1024 thr:
//   16 waves stage (one pass), waves 0-7 compute; uniform barriers.
// ---------------------------------------------------------------------------

typedef unsigned short u16;
typedef short bf16x8 __attribute__((ext_vector_type(8)));
typedef unsigned short ushort8v __attribute__((ext_vector_type(8)));
typedef float f32x4 __attribute__((ext_vector_type(4)));

#define NB 128
#define NT 1024
#define NH 128
#define NM (NB * NT)   // 131072
#define TC 128         // chunk length (steps)
#define NCHUNK (NT / TC)

#define L2E  1.44269504088896f
#define L2E2 2.88539008177793f

__device__ __forceinline__ u16 f2bf(float f) {
  union { float f; unsigned int i; } v; v.f = f;
  unsigned int i = v.i;
  return (u16)((i + 0x7FFFu + ((i >> 16) & 1u)) >> 16);  // RNE
}
__device__ __forceinline__ float bf2f(u16 u) {
  union { unsigned int i; float f; } v; v.i = ((unsigned int)u) << 16; return v.f;
}

#if __has_builtin(__builtin_amdgcn_exp2f)
__device__ __forceinline__ float fast_exp2(float x) { return __builtin_amdgcn_exp2f(x); }
#else
__device__ __forceinline__ float fast_exp2(float x) { return exp2f(x); }
#endif
#if __has_builtin(__builtin_amdgcn_rcpf)
__device__ __forceinline__ float fast_rcp(float x) { return __builtin_amdgcn_rcpf(x); }
#else
__device__ __forceinline__ float fast_rcp(float x) { return 1.0f / x; }
#endif

// ---------------------------------------------------------------------------
// pad w_ih_l0 f32 [512,100] -> bf16 [2][512][128], rows scaled by gate factor
__global__ void padw_kernel(const float* __restrict__ w0, const float* __restrict__ w1,
                            u16* __restrict__ out) {
  int idx = blockIdx.x * 256 + threadIdx.x;  // 131072
  int d = idx >> 16;
  int n = (idx >> 7) & 511;
  int k = idx & 127;
  float sc = ((n >> 7) == 2) ? L2E2 : L2E;
  const float* w = d ? w1 : w0;
  out[idx] = (k < 100) ? f2bf(w[n * 100 + k] * sc) : (u16)0;
}

// fused f32->bf16 convert for 6 weight arrays, rows scaled by gate factor.
__global__ void cvt6_kernel(const float* s0, const float* s1, const float* s2,
                            const float* s3, const float* s4, const float* s5,
                            u16* d0, u16* d1, u16* d2, u16* d3, u16* d4, u16* d5,
                            int n0, int n1, int n2, int n3, int n4, int n5) {
  int y = blockIdx.y;
  const float* s; u16* d; int n; int gs;
  switch (y) {
    case 0: s = s0; d = d0; n = n0; gs = 14; break;
    case 1: s = s1; d = d1; n = n1; gs = 14; break;
    case 2: s = s2; d = d2; n = n2; gs = 14; break;
    case 3: s = s3; d = d3; n = n3; gs = 14; break;
    case 4: s = s4; d = d4; n = n4; gs = 15; break;
    default: s = s5; d = d5; n = n5; gs = 15; break;
  }
  int i = blockIdx.x * 256 + threadIdx.x;
  if (i < n) {
    float sc = (((i >> gs) & 3) == 2) ? L2E2 : L2E;
    d[i] = f2bf(s[i] * sc);
  }
}

// ---------------------------------------------------------------------------
// Fused kernel, 1024 threads/block. Blocks 0..15: lstm chunk `lc` (16 waves,
// r-split pairs). Blocks 16..1039: proj chunk `pc` (16 waves stage, waves
// 0..7 compute 64x32 tiles). xpc layout: [dir*8+wg][sl][rowb(16)][512] bf16.
template <int PK, int LL>
__global__ __launch_bounds__(1024) void fused_chunk(
    int do_lstm, int lc, int pc,
    const float* __restrict__ Aemb, const u16* __restrict__ Ah,
    const int* __restrict__ X,
    const u16* __restrict__ W0, const u16* __restrict__ W1,   // [512][PK] bf16
    const float* __restrict__ bih0, const float* __restrict__ bhh0,
    const float* __restrict__ bih1, const float* __restrict__ bhh1,
    u16* __restrict__ xpc0, u16* __restrict__ xpc1,           // double buffer
    const u16* __restrict__ WHH0, const u16* __restrict__ WHH1,
    u16* __restrict__ OUT, float* __restrict__ FINALS,
    u16* __restrict__ HS, float* __restrict__ CS)
{
  // shared memory union: proj As(18432)+Bs(18432)+toks(512); lstm hb(8704)
  __shared__ __align__(16) unsigned char smem[37888];

  const int tid = threadIdx.x;
  const int lane = tid & 63, wv = tid >> 6;   // wv 0..15
  const int l15 = lane & 15, q = lane >> 4;

  if (blockIdx.x >= 16) {
    // ------------------------- proj part ----------------------------------
    constexpr int BK = 64;
    constexpr int LDA = 72;
    constexpr bool GATHER = (PK == 128);
    u16* As = (u16*)smem;
    u16* Bs = As + 128 * LDA;
    int* toks = (int*)(Bs + 128 * LDA);

    const int pb = blockIdx.x - 16;
    const int b = pb & 127;
    const int gate = (pb >> 7) & 3;
    const int nt0 = gate * 128;
    const int dir = pb >> 9;
    const u16* W = dir ? W1 : W0;
    u16* XPC = (pc & 1) ? xpc1 : xpc0;

    const int wr = wv >> 2, wc = wv & 3;   // waves 0..7 as 2 x 4 (64x32 tiles)

    if (GATHER) {
      if (tid < 128) {
        int t = dir ? (NT - 1 - pc * TC - tid) : (pc * TC + tid);
        toks[tid] = X[b * NT + t];
      }
    }

    f32x4 acc[4][2];
#pragma unroll
    for (int a = 0; a < 4; a++)
#pragma unroll
      for (int bb = 0; bb < 2; bb++)
        acc[a][bb] = (f32x4){0.f, 0.f, 0.f, 0.f};

    const int srow = tid >> 3;        // 0..127 (single staging pass)
    const int sseg = (tid & 7) * 8;   // 0..56

    for (int k0 = 0; k0 < PK; k0 += BK) {
      __syncthreads();   // also covers toks on first iteration
      {
        int row = srow;
        if (GATHER) {
          int tok = toks[row];
          const float* er = Aemb + (size_t)tok * 100;
          int kb = k0 + sseg;
          union { ushort8v v; u16 e[8]; } tu;
          if (kb + 8 <= 100) {
            f32x4 a0 = *(const f32x4*)&er[kb];
            f32x4 a1 = *(const f32x4*)&er[kb + 4];
#pragma unroll
            for (int j = 0; j < 4; j++) { tu.e[j] = f2bf(a0[j]); tu.e[4 + j] = f2bf(a1[j]); }
          } else {
#pragma unroll
            for (int j = 0; j < 8; j++) tu.e[j] = (kb + j < 100) ? f2bf(er[kb + j]) : (u16)0;
          }
          *(ushort8v*)&As[row * LDA + sseg] = tu.v;
        } else {
          int t = dir ? (NT - 1 - pc * TC - row) : (pc * TC + row);
          const u16* srcA = Ah + (size_t)(b * NT + t) * PK + k0 + sseg;
          *(ushort8v*)&As[row * LDA + sseg] = *(const ushort8v*)srcA;
        }
        const u16* srcB = W + (size_t)(nt0 + row) * PK + k0 + sseg;
        *(ushort8v*)&Bs[row * LDA + sseg] = *(const ushort8v*)srcB;
      }
      __syncthreads();
      if (wv < 8) {
#pragma unroll
        for (int kk = 0; kk < BK; kk += 32) {
          bf16x8 af[4], bfr[2];
#pragma unroll
          for (int mt = 0; mt < 4; mt++)
            af[mt] = *(const bf16x8*)&As[(wr * 64 + mt * 16 + l15) * LDA + kk + q * 8];
#pragma unroll
          for (int nt = 0; nt < 2; nt++)
            bfr[nt] = *(const bf16x8*)&Bs[(wc * 32 + nt * 16 + l15) * LDA + kk + q * 8];
#pragma unroll
          for (int mt = 0; mt < 4; mt++)
#pragma unroll
            for (int nt = 0; nt < 2; nt++)
              acc[mt][nt] = __builtin_amdgcn_mfma_f32_16x16x32_bf16(af[mt], bfr[nt], acc[mt][nt], 0, 0, 0);
        }
      }
    }

    if (wv < 8) {
      const float* bih = dir ? bih1 : bih0;
      const float* bhh = dir ? bhh1 : bhh0;
      const float gsc = (gate == 2) ? L2E2 : L2E;
      u16* xo = XPC + (size_t)(dir * 8 + (b >> 4)) * TC * 8192 + (size_t)(b & 15) * 512;
#pragma unroll
      for (int nt = 0; nt < 2; nt++) {
        int n = nt0 + wc * 32 + nt * 16 + l15;
        float bias = (bih[n] + bhh[n]) * gsc;
#pragma unroll
        for (int mt = 0; mt < 4; mt++) {
          int slb = wr * 64 + mt * 16 + q * 4;
#pragma unroll
          for (int r = 0; r < 4; r++)
            xo[(size_t)(slb + r) * 8192 + n] = f2bf(acc[mt][nt][r] + bias);
        }
      }
    }
    return;
  }

  // --------------------------- lstm part (16 waves, r-split pairs) ---------
  if (!do_lstm) return;
  const int wg = blockIdx.x & 7, dir = blockIdx.x >> 3;
  const int cw = wv & 7;          // gate-col wave 0..7
  const int pairi = wv >> 3;      // 0: rows r 0,1 ; 1: rows r 2,3
  const int rb = pairi * 2;
  const int hc = 16 * cw + l15;
  const u16* XPC = (lc & 1) ? xpc1 : xpc0;

  const u16* Wp = dir ? WHH1 : WHH0;
  bf16x8 wf[4][4];
#pragma unroll
  for (int gi = 0; gi < 4; gi++)
#pragma unroll
    for (int kt = 0; kt < 4; kt++)
      wf[gi][kt] = *(const bf16x8*)&Wp[(gi * 128 + hc) * 128 + kt * 32 + q * 8];

  u16* hb = (u16*)smem;  // [2][16*136]

  float cst[2];
  if (lc == 0) {
    for (int i = tid; i < 16 * 136; i += 1024) hb[i] = 0;
#pragma unroll
    for (int rr = 0; rr < 2; rr++) cst[rr] = 0.f;
  } else {
#pragma unroll
    for (int rr = 0; rr < 2; rr++) {
      int row = q * 4 + rb + rr;
      int g = (dir * 128 + wg * 16 + row) * 128 + hc;
      hb[row * 136 + hc] = HS[g];
      cst[rr] = CS[g];
    }
  }

  // lane base into step-contiguous tiles: rows q*4+rb+{0,1}, col hc
  const u16* xb = XPC + (size_t)(dir * 8 + wg) * TC * 8192 + (q * 4 + rb) * 512 + hc;

  // xp regs: [rr*4+gi]; two alternating sets for unroll-2
  float xA[8], xB[8];
#pragma unroll
  for (int rr = 0; rr < 2; rr++)
#pragma unroll
    for (int gi = 0; gi < 4; gi++)
      xA[rr * 4 + gi] = bf2f(xb[rr * 512 + gi * 128]);

  const int t0 = dir ? (NT - 1 - lc * TC) : (lc * TC);
  const int tstep = dir ? -256 : 256;
  u16* optr[2];
  if (LL == 0) {
#pragma unroll
    for (int rr = 0; rr < 2; rr++)
      optr[rr] = OUT + ((size_t)(wg * 16 + q * 4 + rb + rr) * NT + t0) * 256 + dir * 128 + hc;
  }

  __syncthreads();

  int p = 0;
#pragma unroll 1
  for (int sl = 0; sl < TC; sl += 2) {
#pragma unroll
    for (int half = 0; half < 2; half++) {
      const int scur = sl + half;
      float* xcur = half ? xB : xA;
      float* xnxt = half ? xA : xB;

      bf16x8 ah[4];
#pragma unroll
      for (int kt = 0; kt < 4; kt++)
        ah[kt] = *(const bf16x8*)&hb[p * 2176 + l15 * 136 + kt * 32 + q * 8];

      // prefetch step scur+1 (clamped: harmless re-read at the end)
      {
        const int sn = (scur + 1 < TC) ? scur + 1 : scur;
        const u16* nb = xb + (size_t)sn * 8192;
#pragma unroll
        for (int rr = 0; rr < 2; rr++)
#pragma unroll
          for (int gi = 0; gi < 4; gi++)
            xnxt[rr * 4 + gi] = bf2f(nb[rr * 512 + gi * 128]);
      }

      f32x4 acc[4];
#pragma unroll
      for (int gi = 0; gi < 4; gi++) {
#pragma unroll
        for (int r = 0; r < 4; r++) acc[gi][r] = 0.f;
#pragma unroll
        for (int rr = 0; rr < 2; rr++) acc[gi][rb + rr] = xcur[rr * 4 + gi];
      }
#pragma unroll
      for (int gi = 0; gi < 4; gi++)
#pragma unroll
        for (int kt = 0; kt < 4; kt++)
          acc[gi] = __builtin_amdgcn_mfma_f32_16x16x32_bf16(ah[kt], wf[gi][kt], acc[gi], 0, 0, 0);

#pragma unroll
      for (int rr = 0; rr < 2; rr++) {
        const int r = rb + rr;
        // preacts pre-scaled by L2E (i,f,o) / L2E2 (g) via weight folding
        float ei = fast_exp2(acc[0][r]);
        float ef = fast_exp2(acc[1][r]);
        float eg = fast_exp2(acc[2][r]);
        float eo = fast_exp2(acc[3][r]);
        float A = 1.f + ef, B = 1.f + ei, Cg = 1.f + eg;
        float BC = B * Cg;
        float num = cst[rr] * ef * BC + ei * (eg - 1.f) * A;
        float cn = num * fast_rcp(A * BC);
        cst[rr] = cn;
        float ec = fast_exp2(L2E2 * cn);
        float hv = eo * (ec - 1.f) * fast_rcp((1.f + eo) * (1.f + ec));
        u16 hbv = f2bf(hv);
        int row = q * 4 + r;
        hb[(p ^ 1) * 2176 + row * 136 + hc] = hbv;
        if (LL == 0) {
          *optr[rr] = hbv;
          optr[rr] += tstep;
        }
        if (scur == TC - 1) {
          int g = (dir * 128 + wg * 16 + row) * 128 + hc;
          HS[g] = hbv;
          CS[g] = cst[rr];
          if (LL == 1 && lc == NCHUNK - 1)
            FINALS[(wg * 16 + row) * 256 + dir * 128 + hc] = hv;
        }
      }
      __syncthreads();
      p ^= 1;
    }
  }
}

// ---------------------------------------------------------------------------
// fc: out[b][c] = finals[b][:] . fc_w[c][:] + fc_b[c]  (all f32)
__global__ void fc_kernel(const float* __restrict__ finals, const float* __restrict__ fcw,
                          const float* __restrict__ fcb, float* __restrict__ out) {
  int tid = threadIdx.x;  // 256 = 128 b x 2 c
  int b = tid >> 1, cc = tid & 1;
  float s = fcb[cc];
  for (int k = 0; k < 256; k++) s += finals[b * 256 + k] * fcw[cc * 256 + k];
  out[b * 2 + cc] = s;
}

// ---------------------------------------------------------------------------
extern "C" void kernel_launch(void* const* d_in, const int* in_sizes, int n_in,
                              void* d_out, int out_size, void* d_ws, size_t ws_size,
                              hipStream_t stream) {
  const int*   x        = (const int*)d_in[0];
  const float* emb      = (const float*)d_in[1];
  const float* w_ih_l0  = (const float*)d_in[2];
  const float* w_hh_l0  = (const float*)d_in[3];
  const float* b_ih_l0  = (const float*)d_in[4];
  const float* b_hh_l0  = (const float*)d_in[5];
  const float* w_ih_l0r = (const float*)d_in[6];
  const float* w_hh_l0r = (const float*)d_in[7];
  const float* b_ih_l0r = (const float*)d_in[8];
  const float* b_hh_l0r = (const float*)d_in[9];
  const float* w_ih_l1  = (const float*)d_in[10];
  const float* w_hh_l1  = (const float*)d_in[11];
  const float* b_ih_l1  = (const float*)d_in[12];
  const float* b_hh_l1  = (const float*)d_in[13];
  const float* w_ih_l1r = (const float*)d_in[14];
  const float* w_hh_l1r = (const float*)d_in[15];
  const float* b_ih_l1r = (const float*)d_in[16];
  const float* b_hh_l1r = (const float*)d_in[17];
  const float* fc_w     = (const float*)d_in[18];
  const float* fc_b     = (const float*)d_in[19];
  float* out = (float*)d_out;

  // workspace layout — total 135,856,128 B (r8/r9 footprint, proven)
  char* ws = (char*)d_ws;
  size_t off = 0;
  u16*   h1cat = (u16*)(ws + off);   off += 67108864;  // [NM][256] bf16
  u16*   xpc0  = (u16*)(ws + off);   off += 33554432;  // xp double buffer 0
  u16*   xpc1  = (u16*)(ws + off);   off += 33554432;  // xp double buffer 1
  u16*   w0pad = (u16*)(ws + off);   off += 262144;    // [2][512][128] bf16 (scaled)
  u16*   wih1b = (u16*)(ws + off);   off += 524288;    // [2][512][256] bf16 (scaled)
  u16*   whhb  = (u16*)(ws + off);   off += 524288;    // [4][512][128] bf16 (scaled)
  u16*   hs    = (u16*)(ws + off);   off += 65536;     // [2][128][128] bf16
  float* cs    = (float*)(ws + off); off += 131072;    // [2][128][128] f32
  float* fin   = (float*)(ws + off); off += 131072;    // [128][256] f32
  if (ws_size < off) return;  // constant across calls -> same work every call

  hipLaunchKernelGGL(padw_kernel, dim3(512), dim3(256), 0, stream,
                     w_ih_l0, w_ih_l0r, w0pad);
  hipLaunchKernelGGL(cvt6_kernel, dim3(512, 6), dim3(256), 0, stream,
                     w_hh_l0, w_hh_l0r, w_hh_l1, w_hh_l1r, w_ih_l1, w_ih_l1r,
                     whhb, whhb + 65536, whhb + 131072, whhb + 196608,
                     wih1b, wih1b + 131072,
                     65536, 65536, 65536, 65536, 131072, 131072);

  // Layer 0: launch k does proj0(k) [k<8] fused with lstm0(k-1) [k>0]
  for (int k = 0; k <= NCHUNK; k++) {
    int do_proj = (k < NCHUNK);
    int do_lstm = (k > 0);
    hipLaunchKernelGGL((fused_chunk<128, 0>), dim3(do_proj ? 1040 : 16), dim3(1024), 0, stream,
                       do_lstm, k - 1, k,
                       emb, (const u16*)nullptr, x, w0pad, w0pad + 65536,
                       b_ih_l0, b_hh_l0, b_ih_l0r, b_hh_l0r,
                       xpc0, xpc1, whhb, whhb + 65536,
                       h1cat, fin, hs, cs);
  }
  // Layer 1: same pattern, proj reads h1cat (complete after layer-0 phase)
  for (int k = 0; k <= NCHUNK; k++) {
    int do_proj = (k < NCHUNK);
    int do_lstm = (k > 0);
    hipLaunchKernelGGL((fused_chunk<256, 1>), dim3(do_proj ? 1040 : 16), dim3(1024), 0, stream,
                       do_lstm, k - 1, k,
                       (const float*)nullptr, h1cat, (const int*)nullptr,
                       wih1b, wih1b + 131072,
                       b_ih_l1, b_hh_l1, b_ih_l1r, b_hh_l1r,
                       xpc0, xpc1, whhb + 131072, whhb + 196608,
                       h1cat, fin, hs, cs);
  }
  hipLaunchKernelGGL(fc_kernel, dim3(1), dim3(256), 0, stream, fin, fc_w, fc_b, out);
}

// Round 11
// 2192.535 us; speedup vs baseline: 1.3490x; 1.3490x over previous
//
#include <hip/hip_runtime.h>
#include <hip/hip_bf16.h>
#include <stdint.h>

// ---------------------------------------------------------------------------
// BiLSTM classifier: V=50000 E=100 H=128 B=128 T=1024 C=2. f32 I/O.
// Round 11 = r9 (best: 2189 us) with the lstm step barrier replaced by the
// CK block_sync_lds idiom: s_waitcnt lgkmcnt(0) + s_barrier. __syncthreads
// drains vmcnt(0) -> every step paid full global-load latency for the xp
// prefetch + OUT stores (~1000 cyc/step). LDS-only drain lets VMEM latency
// span the barrier; loads wait at their USE one step later.
// ---------------------------------------------------------------------------

typedef unsigned short u16;
typedef short bf16x8 __attribute__((ext_vector_type(8)));
typedef unsigned short ushort8v __attribute__((ext_vector_type(8)));
typedef float f32x4 __attribute__((ext_vector_type(4)));

#define NB 128
#define NT 1024
#define NH 128
#define NM (NB * NT)   // 131072
#define TC 128         // chunk length (steps)
#define NCHUNK (NT / TC)

#define L2E  1.44269504088896f
#define L2E2 2.88539008177793f

__device__ __forceinline__ u16 f2bf(float f) {
  union { float f; unsigned int i; } v; v.f = f;
  unsigned int i = v.i;
  return (u16)((i + 0x7FFFu + ((i >> 16) & 1u)) >> 16);  // RNE
}
__device__ __forceinline__ float bf2f(u16 u) {
  union { unsigned int i; float f; } v; v.i = ((unsigned int)u) << 16; return v.f;
}

#if __has_builtin(__builtin_amdgcn_exp2f)
__device__ __forceinline__ float fast_exp2(float x) { return __builtin_amdgcn_exp2f(x); }
#else
__device__ __forceinline__ float fast_exp2(float x) { return exp2f(x); }
#endif
#if __has_builtin(__builtin_amdgcn_rcpf)
__device__ __forceinline__ float fast_rcp(float x) { return __builtin_amdgcn_rcpf(x); }
#else
__device__ __forceinline__ float fast_rcp(float x) { return 1.0f / x; }
#endif

// LDS-only workgroup sync (composable_kernel block_sync_lds pattern):
// waits LDS ops (lgkmcnt=0) but leaves global loads/stores in flight
// (vmcnt=63, expcnt=7 -> imm 0xc07f on gfx9).
__device__ __forceinline__ void sync_lds() {
  __builtin_amdgcn_s_waitcnt(0xc07f);
  __builtin_amdgcn_s_barrier();
}

// ---------------------------------------------------------------------------
// pad w_ih_l0 f32 [512,100] -> bf16 [2][512][128], rows scaled by gate factor
__global__ void padw_kernel(const float* __restrict__ w0, const float* __restrict__ w1,
                            u16* __restrict__ out) {
  int idx = blockIdx.x * 256 + threadIdx.x;  // 131072
  int d = idx >> 16;
  int n = (idx >> 7) & 511;
  int k = idx & 127;
  float sc = ((n >> 7) == 2) ? L2E2 : L2E;
  const float* w = d ? w1 : w0;
  out[idx] = (k < 100) ? f2bf(w[n * 100 + k] * sc) : (u16)0;
}

// fused f32->bf16 convert for 6 weight arrays, rows scaled by gate factor.
__global__ void cvt6_kernel(const float* s0, const float* s1, const float* s2,
                            const float* s3, const float* s4, const float* s5,
                            u16* d0, u16* d1, u16* d2, u16* d3, u16* d4, u16* d5,
                            int n0, int n1, int n2, int n3, int n4, int n5) {
  int y = blockIdx.y;
  const float* s; u16* d; int n; int gs;
  switch (y) {
    case 0: s = s0; d = d0; n = n0; gs = 14; break;
    case 1: s = s1; d = d1; n = n1; gs = 14; break;
    case 2: s = s2; d = d2; n = n2; gs = 14; break;
    case 3: s = s3; d = d3; n = n3; gs = 14; break;
    case 4: s = s4; d = d4; n = n4; gs = 15; break;
    default: s = s5; d = d5; n = n5; gs = 15; break;
  }
  int i = blockIdx.x * 256 + threadIdx.x;
  if (i < n) {
    float sc = (((i >> gs) & 3) == 2) ? L2E2 : L2E;
    d[i] = f2bf(s[i] * sc);
  }
}

// ---------------------------------------------------------------------------
// Fused kernel. Blocks 0..15: lstm chunk `lc` (if do_lstm). Blocks 16..1039:
// proj chunk `pc` (grid sized to 16 when do_proj==0).
// xpc layout: [dir*8+wg][sl][rowb(16)][512] bf16 (step-contiguous 16KB tiles).
template <int PK, int LL>
__global__ __launch_bounds__(512) void fused_chunk(
    int do_lstm, int lc, int pc,
    const float* __restrict__ Aemb, const u16* __restrict__ Ah,
    const int* __restrict__ X,
    const u16* __restrict__ W0, const u16* __restrict__ W1,   // [512][PK] bf16
    const float* __restrict__ bih0, const float* __restrict__ bhh0,
    const float* __restrict__ bih1, const float* __restrict__ bhh1,
    u16* __restrict__ xpc0, u16* __restrict__ xpc1,           // double buffer
    const u16* __restrict__ WHH0, const u16* __restrict__ WHH1,
    u16* __restrict__ OUT, float* __restrict__ FINALS,
    u16* __restrict__ HS, float* __restrict__ CS)
{
  // shared memory union: proj As(18432)+Bs(18432)+toks(512); lstm hb(8704)
  __shared__ __align__(16) unsigned char smem[37888];

  const int tid = threadIdx.x;
  const int lane = tid & 63, wv = tid >> 6;
  const int l15 = lane & 15, q = lane >> 4;

  if (blockIdx.x >= 16) {
    // ------------------------- proj part (8 waves, 64x32 wave tiles) -------
    constexpr int BK = 64;
    constexpr int LDA = 72;
    constexpr bool GATHER = (PK == 128);
    u16* As = (u16*)smem;
    u16* Bs = As + 128 * LDA;
    int* toks = (int*)(Bs + 128 * LDA);

    const int pb = blockIdx.x - 16;
    const int b = pb & 127;
    const int gate = (pb >> 7) & 3;
    const int nt0 = gate * 128;
    const int dir = pb >> 9;
    const u16* W = dir ? W1 : W0;
    u16* XPC = (pc & 1) ? xpc1 : xpc0;

    const int wr = wv >> 2, wc = wv & 3;   // 2 x 4 waves

    if (GATHER) {
      if (tid < 128) {
        int t = dir ? (NT - 1 - pc * TC - tid) : (pc * TC + tid);
        toks[tid] = X[b * NT + t];
      }
    }

    f32x4 acc[4][2];
#pragma unroll
    for (int a = 0; a < 4; a++)
#pragma unroll
      for (int bb = 0; bb < 2; bb++)
        acc[a][bb] = (f32x4){0.f, 0.f, 0.f, 0.f};

    const int srow = tid >> 3;        // 0..63
    const int sseg = (tid & 7) * 8;   // 0..56

    for (int k0 = 0; k0 < PK; k0 += BK) {
      __syncthreads();   // also covers toks on first iteration
#pragma unroll
      for (int p = 0; p < 2; p++) {
        int row = srow + p * 64;
        if (GATHER) {
          int tok = toks[row];
          const float* er = Aemb + (size_t)tok * 100;
          int kb = k0 + sseg;
          union { ushort8v v; u16 e[8]; } tu;
          if (kb + 8 <= 100) {
            f32x4 a0 = *(const f32x4*)&er[kb];
            f32x4 a1 = *(const f32x4*)&er[kb + 4];
#pragma unroll
            for (int j = 0; j < 4; j++) { tu.e[j] = f2bf(a0[j]); tu.e[4 + j] = f2bf(a1[j]); }
          } else {
#pragma unroll
            for (int j = 0; j < 8; j++) tu.e[j] = (kb + j < 100) ? f2bf(er[kb + j]) : (u16)0;
          }
          *(ushort8v*)&As[row * LDA + sseg] = tu.v;
        } else {
          int t = dir ? (NT - 1 - pc * TC - row) : (pc * TC + row);
          const u16* srcA = Ah + (size_t)(b * NT + t) * PK + k0 + sseg;
          *(ushort8v*)&As[row * LDA + sseg] = *(const ushort8v*)srcA;
        }
        const u16* srcB = W + (size_t)(nt0 + row) * PK + k0 + sseg;
        *(ushort8v*)&Bs[row * LDA + sseg] = *(const ushort8v*)srcB;
      }
      __syncthreads();
#pragma unroll
      for (int kk = 0; kk < BK; kk += 32) {
        bf16x8 af[4], bfr[2];
#pragma unroll
        for (int mt = 0; mt < 4; mt++)
          af[mt] = *(const bf16x8*)&As[(wr * 64 + mt * 16 + l15) * LDA + kk + q * 8];
#pragma unroll
        for (int nt = 0; nt < 2; nt++)
          bfr[nt] = *(const bf16x8*)&Bs[(wc * 32 + nt * 16 + l15) * LDA + kk + q * 8];
#pragma unroll
        for (int mt = 0; mt < 4; mt++)
#pragma unroll
          for (int nt = 0; nt < 2; nt++)
            acc[mt][nt] = __builtin_amdgcn_mfma_f32_16x16x32_bf16(af[mt], bfr[nt], acc[mt][nt], 0, 0, 0);
      }
    }

    const float* bih = dir ? bih1 : bih0;
    const float* bhh = dir ? bhh1 : bhh0;
    const float gsc = (gate == 2) ? L2E2 : L2E;
    // step-contiguous tile base for (dir, wg=b>>4), row rowb=b&15
    u16* xo = XPC + (size_t)(dir * 8 + (b >> 4)) * TC * 8192 + (size_t)(b & 15) * 512;
#pragma unroll
    for (int nt = 0; nt < 2; nt++) {
      int n = nt0 + wc * 32 + nt * 16 + l15;
      float bias = (bih[n] + bhh[n]) * gsc;
#pragma unroll
      for (int mt = 0; mt < 4; mt++) {
        int slb = wr * 64 + mt * 16 + q * 4;   // step-local index base
#pragma unroll
        for (int r = 0; r < 4; r++)
          xo[(size_t)(slb + r) * 8192 + n] = f2bf(acc[mt][nt][r] + bias);
      }
    }
    return;
  }

  // --------------------------- lstm part -----------------------------------
  if (!do_lstm) return;
  const int wg = blockIdx.x & 7, dir = blockIdx.x >> 3;
  const int hc = 16 * wv + l15;
  const u16* XPC = (lc & 1) ? xpc1 : xpc0;

  const u16* Wp = dir ? WHH1 : WHH0;
  bf16x8 wf[4][4];
#pragma unroll
  for (int gi = 0; gi < 4; gi++)
#pragma unroll
    for (int kt = 0; kt < 4; kt++)
      wf[gi][kt] = *(const bf16x8*)&Wp[(gi * 128 + hc) * 128 + kt * 32 + q * 8];

  u16* hb = (u16*)smem;  // [2][16*136]

  float cst[4];
  if (lc == 0) {
    for (int i = tid; i < 16 * 136; i += 512) hb[i] = 0;
#pragma unroll
    for (int r = 0; r < 4; r++) cst[r] = 0.f;
  } else {
#pragma unroll
    for (int r = 0; r < 4; r++) {
      int row = q * 4 + r;
      int g = (dir * 128 + wg * 16 + row) * 128 + hc;
      hb[row * 136 + hc] = HS[g];
      cst[r] = CS[g];
    }
  }

  // lane base into step-contiguous tiles: + row-base (q*4)*512 + col hc
  const u16* xb = XPC + (size_t)(dir * 8 + wg) * TC * 8192 + (q * 4) * 512 + hc;

  // xp regs: [r*4+gi] ; two alternating sets for unroll-2
  float xA[16], xB[16];
#pragma unroll
  for (int r = 0; r < 4; r++)
#pragma unroll
    for (int gi = 0; gi < 4; gi++)
      xA[r * 4 + gi] = bf2f(xb[r * 512 + gi * 128]);

  const int t0 = dir ? (NT - 1 - lc * TC) : (lc * TC);
  const int tstep = dir ? -256 : 256;
  u16* optr[4];
  if (LL == 0) {
#pragma unroll
    for (int r = 0; r < 4; r++)
      optr[r] = OUT + ((size_t)(wg * 16 + q * 4 + r) * NT + t0) * 256 + dir * 128 + hc;
  }

  __syncthreads();

  int p = 0;
#pragma unroll 1
  for (int sl = 0; sl < TC; sl += 2) {
#pragma unroll
    for (int half = 0; half < 2; half++) {
      const int scur = sl + half;
      float* xcur = half ? xB : xA;
      float* xnxt = half ? xA : xB;

      bf16x8 ah[4];
#pragma unroll
      for (int kt = 0; kt < 4; kt++)
        ah[kt] = *(const bf16x8*)&hb[p * 2176 + l15 * 136 + kt * 32 + q * 8];

      // prefetch step scur+1 (clamped: harmless re-read at the end)
      {
        const int sn = (scur + 1 < TC) ? scur + 1 : scur;
        const u16* nb = xb + (size_t)sn * 8192;
#pragma unroll
        for (int r = 0; r < 4; r++)
#pragma unroll
          for (int gi = 0; gi < 4; gi++)
            xnxt[r * 4 + gi] = bf2f(nb[r * 512 + gi * 128]);
      }

      f32x4 acc[4];
#pragma unroll
      for (int gi = 0; gi < 4; gi++)
#pragma unroll
        for (int r = 0; r < 4; r++)
          acc[gi][r] = xcur[r * 4 + gi];
#pragma unroll
      for (int gi = 0; gi < 4; gi++)
#pragma unroll
        for (int kt = 0; kt < 4; kt++)
          acc[gi] = __builtin_amdgcn_mfma_f32_16x16x32_bf16(ah[kt], wf[gi][kt], acc[gi], 0, 0, 0);

#pragma unroll
      for (int r = 0; r < 4; r++) {
        // preacts pre-scaled by L2E (i,f,o) / L2E2 (g) via weight folding
        float ei = fast_exp2(acc[0][r]);
        float ef = fast_exp2(acc[1][r]);
        float eg = fast_exp2(acc[2][r]);
        float eo = fast_exp2(acc[3][r]);
        float A = 1.f + ef, B = 1.f + ei, Cg = 1.f + eg;
        float BC = B * Cg;
        float num = cst[r] * ef * BC + ei * (eg - 1.f) * A;
        float cn = num * fast_rcp(A * BC);
        cst[r] = cn;
        float ec = fast_exp2(L2E2 * cn);
        float hv = eo * (ec - 1.f) * fast_rcp((1.f + eo) * (1.f + ec));
        u16 hbv = f2bf(hv);
        int row = q * 4 + r;
        hb[(p ^ 1) * 2176 + row * 136 + hc] = hbv;
        if (LL == 0) {
          *optr[r] = hbv;
          optr[r] += tstep;
        }
        if (scur == TC - 1) {
          int g = (dir * 128 + wg * 16 + row) * 128 + hc;
          HS[g] = hbv;
          CS[g] = cst[r];
          if (LL == 1 && lc == NCHUNK - 1)
            FINALS[(wg * 16 + row) * 256 + dir * 128 + hc] = hv;
        }
      }
      // LDS-only barrier: h-exchange needs lgkmcnt(0)+arrival, NOT vmcnt(0).
      // Global prefetch loads/OUT stores stay in flight across steps.
      sync_lds();
      p ^= 1;
    }
  }
}

// ---------------------------------------------------------------------------
// fc: out[b][c] = finals[b][:] . fc_w[c][:] + fc_b[c]  (all f32)
__global__ void fc_kernel(const float* __restrict__ finals, const float* __restrict__ fcw,
                          const float* __restrict__ fcb, float* __restrict__ out) {
  int tid = threadIdx.x;  // 256 = 128 b x 2 c
  int b = tid >> 1, cc = tid & 1;
  float s = fcb[cc];
  for (int k = 0; k < 256; k++) s += finals[b * 256 + k] * fcw[cc * 256 + k];
  out[b * 2 + cc] = s;
}

// ---------------------------------------------------------------------------
extern "C" void kernel_launch(void* const* d_in, const int* in_sizes, int n_in,
                              void* d_out, int out_size, void* d_ws, size_t ws_size,
                              hipStream_t stream) {
  const int*   x        = (const int*)d_in[0];
  const float* emb      = (const float*)d_in[1];
  const float* w_ih_l0  = (const float*)d_in[2];
  const float* w_hh_l0  = (const float*)d_in[3];
  const float* b_ih_l0  = (const float*)d_in[4];
  const float* b_hh_l0  = (const float*)d_in[5];
  const float* w_ih_l0r = (const float*)d_in[6];
  const float* w_hh_l0r = (const float*)d_in[7];
  const float* b_ih_l0r = (const float*)d_in[8];
  const float* b_hh_l0r = (const float*)d_in[9];
  const float* w_ih_l1  = (const float*)d_in[10];
  const float* w_hh_l1  = (const float*)d_in[11];
  const float* b_ih_l1  = (const float*)d_in[12];
  const float* b_hh_l1  = (const float*)d_in[13];
  const float* w_ih_l1r = (const float*)d_in[14];
  const float* w_hh_l1r = (const float*)d_in[15];
  const float* b_ih_l1r = (const float*)d_in[16];
  const float* b_hh_l1r = (const float*)d_in[17];
  const float* fc_w     = (const float*)d_in[18];
  const float* fc_b     = (const float*)d_in[19];
  float* out = (float*)d_out;

  // workspace layout — total 135,856,128 B (r8/r9 footprint, proven)
  char* ws = (char*)d_ws;
  size_t off = 0;
  u16*   h1cat = (u16*)(ws + off);   off += 67108864;  // [NM][256] bf16
  u16*   xpc0  = (u16*)(ws + off);   off += 33554432;  // xp double buffer 0
  u16*   xpc1  = (u16*)(ws + off);   off += 33554432;  // xp double buffer 1
  u16*   w0pad = (u16*)(ws + off);   off += 262144;    // [2][512][128] bf16 (scaled)
  u16*   wih1b = (u16*)(ws + off);   off += 524288;    // [2][512][256] bf16 (scaled)
  u16*   whhb  = (u16*)(ws + off);   off += 524288;    // [4][512][128] bf16 (scaled)
  u16*   hs    = (u16*)(ws + off);   off += 65536;     // [2][128][128] bf16
  float* cs    = (float*)(ws + off); off += 131072;    // [2][128][128] f32
  float* fin   = (float*)(ws + off); off += 131072;    // [128][256] f32
  if (ws_size < off) return;  // constant across calls -> same work every call

  hipLaunchKernelGGL(padw_kernel, dim3(512), dim3(256), 0, stream,
                     w_ih_l0, w_ih_l0r, w0pad);
  hipLaunchKernelGGL(cvt6_kernel, dim3(512, 6), dim3(256), 0, stream,
                     w_hh_l0, w_hh_l0r, w_hh_l1, w_hh_l1r, w_ih_l1, w_ih_l1r,
                     whhb, whhb + 65536, whhb + 131072, whhb + 196608,
                     wih1b, wih1b + 131072,
                     65536, 65536, 65536, 65536, 131072, 131072);

  // Layer 0: launch k does proj0(k) [k<8] fused with lstm0(k-1) [k>0]
  for (int k = 0; k <= NCHUNK; k++) {
    int do_proj = (k < NCHUNK);
    int do_lstm = (k > 0);
    hipLaunchKernelGGL((fused_chunk<128, 0>), dim3(do_proj ? 1040 : 16), dim3(512), 0, stream,
                       do_lstm, k - 1, k,
                       emb, (const u16*)nullptr, x, w0pad, w0pad + 65536,
                       b_ih_l0, b_hh_l0, b_ih_l0r, b_hh_l0r,
                       xpc0, xpc1, whhb, whhb + 65536,
                       h1cat, fin, hs, cs);
  }
  // Layer 1: same pattern, proj reads h1cat (complete after layer-0 phase)
  for (int k = 0; k <= NCHUNK; k++) {
    int do_proj = (k < NCHUNK);
    int do_lstm = (k > 0);
    hipLaunchKernelGGL((fused_chunk<256, 1>), dim3(do_proj ? 1040 : 16), dim3(512), 0, stream,
                       do_lstm, k - 1, k,
                       (const float*)nullptr, h1cat, (const int*)nullptr,
                       wih1b, wih1b + 131072,
                       b_ih_l1, b_hh_l1, b_ih_l1r, b_hh_l1r,
                       xpc0, xpc1, whhb + 131072, whhb + 196608,
                       h1cat, fin, hs, cs);
  }
  hipLaunchKernelGGL(fc_kernel, dim3(1), dim3(256), 0, stream, fin, fc_w, fc_b, out);
}

// Round 12
// 1986.800 us; speedup vs baseline: 1.4886x; 1.1036x over previous
//
#include <hip/hip_runtime.h>
#include <hip/hip_bf16.h>
#include <stdint.h>

// ---------------------------------------------------------------------------
// BiLSTM classifier: V=50000 E=100 H=128 B=128 T=1024 C=2. f32 I/O.
// Round 12 = r11 + batch-split lstm (32 WGs x 8 rows, independent chains) +
// in-wave C-fragment remap: after MFMA (M=16, rows 8..15 zero), each wave
// redistributes its 128 valid gate-sets over all 64 lanes via a wave-internal
// LDS roundtrip (4 masked ds_write_b128 + 4 ds_read_b64, no barrier) ->
// 2 gate-sets/lane instead of 4: trans 28->14, gate VALU ~72->36, xp loads
// 16->8. Empirical law from r5..r11: step time ~ per-lane instruction count
// (chain-latency bound, ~20 cyc/instr); this halves the dominant term.
// xp added AFTER remap (MFMA C-init = zero vector, no per-step acc copies).
// ---------------------------------------------------------------------------

typedef unsigned short u16;
typedef short bf16x8 __attribute__((ext_vector_type(8)));
typedef unsigned short ushort8v __attribute__((ext_vector_type(8)));
typedef float f32x4 __attribute__((ext_vector_type(4)));
typedef float f32x2 __attribute__((ext_vector_type(2)));

#define NB 128
#define NT 1024
#define NH 128
#define NM (NB * NT)   // 131072
#define TC 128         // chunk length (steps)
#define NCHUNK (NT / TC)

#define L2E  1.44269504088896f
#define L2E2 2.88539008177793f

__device__ __forceinline__ u16 f2bf(float f) {
  union { float f; unsigned int i; } v; v.f = f;
  unsigned int i = v.i;
  return (u16)((i + 0x7FFFu + ((i >> 16) & 1u)) >> 16);  // RNE
}
__device__ __forceinline__ float bf2f(u16 u) {
  union { unsigned int i; float f; } v; v.i = ((unsigned int)u) << 16; return v.f;
}

#if __has_builtin(__builtin_amdgcn_exp2f)
__device__ __forceinline__ float fast_exp2(float x) { return __builtin_amdgcn_exp2f(x); }
#else
__device__ __forceinline__ float fast_exp2(float x) { return exp2f(x); }
#endif
#if __has_builtin(__builtin_amdgcn_rcpf)
__device__ __forceinline__ float fast_rcp(float x) { return __builtin_amdgcn_rcpf(x); }
#else
__device__ __forceinline__ float fast_rcp(float x) { return 1.0f / x; }
#endif

// LDS-only waits: lgkmcnt(0), vmcnt/expcnt unconstrained (imm 0xc07f, gfx9).
__device__ __forceinline__ void wait_lds() { __builtin_amdgcn_s_waitcnt(0xc07f); }
__device__ __forceinline__ void sync_lds() {
  __builtin_amdgcn_s_waitcnt(0xc07f);
  __builtin_amdgcn_s_barrier();
}

// ---------------------------------------------------------------------------
// pad w_ih_l0 f32 [512,100] -> bf16 [2][512][128], rows scaled by gate factor
__global__ void padw_kernel(const float* __restrict__ w0, const float* __restrict__ w1,
                            u16* __restrict__ out) {
  int idx = blockIdx.x * 256 + threadIdx.x;  // 131072
  int d = idx >> 16;
  int n = (idx >> 7) & 511;
  int k = idx & 127;
  float sc = ((n >> 7) == 2) ? L2E2 : L2E;
  const float* w = d ? w1 : w0;
  out[idx] = (k < 100) ? f2bf(w[n * 100 + k] * sc) : (u16)0;
}

// fused f32->bf16 convert for 6 weight arrays, rows scaled by gate factor.
__global__ void cvt6_kernel(const float* s0, const float* s1, const float* s2,
                            const float* s3, const float* s4, const float* s5,
                            u16* d0, u16* d1, u16* d2, u16* d3, u16* d4, u16* d5,
                            int n0, int n1, int n2, int n3, int n4, int n5) {
  int y = blockIdx.y;
  const float* s; u16* d; int n; int gs;
  switch (y) {
    case 0: s = s0; d = d0; n = n0; gs = 14; break;
    case 1: s = s1; d = d1; n = n1; gs = 14; break;
    case 2: s = s2; d = d2; n = n2; gs = 14; break;
    case 3: s = s3; d = d3; n = n3; gs = 14; break;
    case 4: s = s4; d = d4; n = n4; gs = 15; break;
    default: s = s5; d = d5; n = n5; gs = 15; break;
  }
  int i = blockIdx.x * 256 + threadIdx.x;
  if (i < n) {
    float sc = (((i >> gs) & 3) == 2) ? L2E2 : L2E;
    d[i] = f2bf(s[i] * sc);
  }
}

// ---------------------------------------------------------------------------
// Fused kernel. Blocks 0..31: lstm chunk `lc` (8 batch rows each, 2 dirs x
// 16 wg). Blocks 32..1055: proj chunk `pc`.
// xpc layout: [dir*16+wg][sl][rowb(8)][512] bf16 (step-contiguous 8KB tiles).
template <int PK, int LL>
__global__ __launch_bounds__(512) void fused_chunk(
    int do_lstm, int lc, int pc,
    const float* __restrict__ Aemb, const u16* __restrict__ Ah,
    const int* __restrict__ X,
    const u16* __restrict__ W0, const u16* __restrict__ W1,   // [512][PK] bf16
    const float* __restrict__ bih0, const float* __restrict__ bhh0,
    const float* __restrict__ bih1, const float* __restrict__ bhh1,
    u16* __restrict__ xpc0, u16* __restrict__ xpc1,           // double buffer
    const u16* __restrict__ WHH0, const u16* __restrict__ WHH1,
    u16* __restrict__ OUT, float* __restrict__ FINALS,
    u16* __restrict__ HS, float* __restrict__ CS)
{
  // smem: proj As(18432)+Bs(18432)+toks(512)=37376; lstm hb(8704)+remap(16K)
  __shared__ __align__(16) unsigned char smem[37888];

  const int tid = threadIdx.x;
  const int lane = tid & 63, wv = tid >> 6;
  const int l15 = lane & 15, q = lane >> 4;

  if (blockIdx.x >= 32) {
    // ------------------------- proj part (8 waves, 64x32 wave tiles) -------
    constexpr int BK = 64;
    constexpr int LDA = 72;
    constexpr bool GATHER = (PK == 128);
    u16* As = (u16*)smem;
    u16* Bs = As + 128 * LDA;
    int* toks = (int*)(Bs + 128 * LDA);

    const int pb = blockIdx.x - 32;
    const int b = pb & 127;
    const int gate = (pb >> 7) & 3;
    const int nt0 = gate * 128;
    const int dir = pb >> 9;
    const u16* W = dir ? W1 : W0;
    u16* XPC = (pc & 1) ? xpc1 : xpc0;

    const int wr = wv >> 2, wc = wv & 3;   // 2 x 4 waves

    if (GATHER) {
      if (tid < 128) {
        int t = dir ? (NT - 1 - pc * TC - tid) : (pc * TC + tid);
        toks[tid] = X[b * NT + t];
      }
    }

    f32x4 acc[4][2];
#pragma unroll
    for (int a = 0; a < 4; a++)
#pragma unroll
      for (int bb = 0; bb < 2; bb++)
        acc[a][bb] = (f32x4){0.f, 0.f, 0.f, 0.f};

    const int srow = tid >> 3;        // 0..63
    const int sseg = (tid & 7) * 8;   // 0..56

    for (int k0 = 0; k0 < PK; k0 += BK) {
      __syncthreads();   // also covers toks on first iteration
#pragma unroll
      for (int p = 0; p < 2; p++) {
        int row = srow + p * 64;
        if (GATHER) {
          int tok = toks[row];
          const float* er = Aemb + (size_t)tok * 100;
          int kb = k0 + sseg;
          union { ushort8v v; u16 e[8]; } tu;
          if (kb + 8 <= 100) {
            f32x4 a0 = *(const f32x4*)&er[kb];
            f32x4 a1 = *(const f32x4*)&er[kb + 4];
#pragma unroll
            for (int j = 0; j < 4; j++) { tu.e[j] = f2bf(a0[j]); tu.e[4 + j] = f2bf(a1[j]); }
          } else {
#pragma unroll
            for (int j = 0; j < 8; j++) tu.e[j] = (kb + j < 100) ? f2bf(er[kb + j]) : (u16)0;
          }
          *(ushort8v*)&As[row * LDA + sseg] = tu.v;
        } else {
          int t = dir ? (NT - 1 - pc * TC - row) : (pc * TC + row);
          const u16* srcA = Ah + (size_t)(b * NT + t) * PK + k0 + sseg;
          *(ushort8v*)&As[row * LDA + sseg] = *(const ushort8v*)srcA;
        }
        const u16* srcB = W + (size_t)(nt0 + row) * PK + k0 + sseg;
        *(ushort8v*)&Bs[row * LDA + sseg] = *(const ushort8v*)srcB;
      }
      __syncthreads();
#pragma unroll
      for (int kk = 0; kk < BK; kk += 32) {
        bf16x8 af[4], bfr[2];
#pragma unroll
        for (int mt = 0; mt < 4; mt++)
          af[mt] = *(const bf16x8*)&As[(wr * 64 + mt * 16 + l15) * LDA + kk + q * 8];
#pragma unroll
        for (int nt = 0; nt < 2; nt++)
          bfr[nt] = *(const bf16x8*)&Bs[(wc * 32 + nt * 16 + l15) * LDA + kk + q * 8];
#pragma unroll
        for (int mt = 0; mt < 4; mt++)
#pragma unroll
          for (int nt = 0; nt < 2; nt++)
            acc[mt][nt] = __builtin_amdgcn_mfma_f32_16x16x32_bf16(af[mt], bfr[nt], acc[mt][nt], 0, 0, 0);
      }
    }

    const float* bih = dir ? bih1 : bih0;
    const float* bhh = dir ? bhh1 : bhh0;
    const float gsc = (gate == 2) ? L2E2 : L2E;
    // 8-row step tiles: tile (dir*16 + b>>3), row rowb = b&7
    u16* xo = XPC + (size_t)(dir * 16 + (b >> 3)) * TC * 4096 + (size_t)(b & 7) * 512;
#pragma unroll
    for (int nt = 0; nt < 2; nt++) {
      int n = nt0 + wc * 32 + nt * 16 + l15;
      float bias = (bih[n] + bhh[n]) * gsc;
#pragma unroll
      for (int mt = 0; mt < 4; mt++) {
        int slb = wr * 64 + mt * 16 + q * 4;   // step-local index base
#pragma unroll
        for (int r = 0; r < 4; r++)
          xo[(size_t)(slb + r) * 4096 + n] = f2bf(acc[mt][nt][r] + bias);
      }
    }
    return;
  }

  // --------------------------- lstm part (8 rows/WG + in-wave remap) -------
  if (!do_lstm) return;
  const int wg = blockIdx.x & 15, dir = blockIdx.x >> 4;
  const int hc = 16 * wv + l15;
  const u16* XPC = (lc & 1) ? xpc1 : xpc0;

  const u16* Wp = dir ? WHH1 : WHH0;
  bf16x8 wf[4][4];
#pragma unroll
  for (int gi = 0; gi < 4; gi++)
#pragma unroll
    for (int kt = 0; kt < 4; kt++)
      wf[gi][kt] = *(const bf16x8*)&Wp[(gi * 128 + hc) * 128 + kt * 32 + q * 8];

  u16* hb = (u16*)smem;                               // [2][16*136] u16
  float* wsc = (float*)(smem + 8704 + wv * 2048);     // per-wave remap scratch

  float cst[2];
  if (lc == 0) {
    for (int i = tid; i < 2 * 16 * 136; i += 512) hb[i] = 0;
#pragma unroll
    for (int rr = 0; rr < 2; rr++) cst[rr] = 0.f;
  } else {
    // zero rows 8..15 of both planes (MFMA garbage guard)
    for (int i = tid; i < 2 * 8 * 136; i += 512) {
      int pl = i / (8 * 136), j = i - pl * (8 * 136);
      hb[pl * 2176 + 8 * 136 + j] = 0;
    }
    // load rows 0..7 (this lane owns rows 2q, 2q+1 at col hc)
#pragma unroll
    for (int rr = 0; rr < 2; rr++) {
      int row = 2 * q + rr;
      int g = (dir * 128 + wg * 8 + row) * 128 + hc;
      hb[row * 136 + hc] = HS[g];
      cst[rr] = CS[g];
    }
  }

  // xp lane base: rows {2q, 2q+1}, col hc; per-step stride 4096 u16 (8KB)
  const u16* xb = XPC + (size_t)(dir * 16 + wg) * TC * 4096 + (2 * q) * 512 + hc;

  // xp regs: [rr*4+gi]; two alternating sets for unroll-2
  float xA[8], xB[8];
#pragma unroll
  for (int rr = 0; rr < 2; rr++)
#pragma unroll
    for (int gi = 0; gi < 4; gi++)
      xA[rr * 4 + gi] = bf2f(xb[rr * 512 + gi * 128]);

  const int t0 = dir ? (NT - 1 - lc * TC) : (lc * TC);
  const int tstep = dir ? -256 : 256;
  u16* optr[2];
  if (LL == 0) {
#pragma unroll
    for (int rr = 0; rr < 2; rr++)
      optr[rr] = OUT + ((size_t)(wg * 8 + 2 * q + rr) * NT + t0) * 256 + dir * 128 + hc;
  }

  const f32x4 zero4 = {0.f, 0.f, 0.f, 0.f};

  __syncthreads();

  int p = 0;
#pragma unroll 1
  for (int sl = 0; sl < TC; sl += 2) {
#pragma unroll
    for (int half = 0; half < 2; half++) {
      const int scur = sl + half;
      float* xcur = half ? xB : xA;
      float* xnxt = half ? xA : xB;

      bf16x8 ah[4];
#pragma unroll
      for (int kt = 0; kt < 4; kt++)
        ah[kt] = *(const bf16x8*)&hb[p * 2176 + l15 * 136 + kt * 32 + q * 8];

      // prefetch step scur+1 (clamped: harmless re-read at the end)
      {
        const int sn = (scur + 1 < TC) ? scur + 1 : scur;
        const u16* nb = xb + (size_t)sn * 4096;
#pragma unroll
        for (int rr = 0; rr < 2; rr++)
#pragma unroll
          for (int gi = 0; gi < 4; gi++)
            xnxt[rr * 4 + gi] = bf2f(nb[rr * 512 + gi * 128]);
      }

      // MFMA with zero C-init (xp added after remap)
      f32x4 acc[4];
#pragma unroll
      for (int gi = 0; gi < 4; gi++) {
        acc[gi] = __builtin_amdgcn_mfma_f32_16x16x32_bf16(ah[0], wf[gi][0], zero4, 0, 0, 0);
#pragma unroll
        for (int kt = 1; kt < 4; kt++)
          acc[gi] = __builtin_amdgcn_mfma_f32_16x16x32_bf16(ah[kt], wf[gi][kt], acc[gi], 0, 0, 0);
      }

      // in-wave remap: valid rows live in lanes q<2 (C rows q*4+r < 8);
      // scratch layout [gi][col l15][row 0..7] f32 -> each lane picks up
      // rows {2q, 2q+1} at its col. Wave-internal: lgkm wait, no barrier.
      if (lane < 32) {
#pragma unroll
        for (int gi = 0; gi < 4; gi++)
          *(f32x4*)&wsc[gi * 128 + l15 * 8 + (lane >> 4) * 4] = acc[gi];
      }
      wait_lds();
      f32x2 ar[4];
#pragma unroll
      for (int gi = 0; gi < 4; gi++)
        ar[gi] = *(const f32x2*)&wsc[gi * 128 + l15 * 8 + q * 2];

#pragma unroll
      for (int rr = 0; rr < 2; rr++) {
        // preacts pre-scaled by L2E/L2E2 via weight folding; + xp after remap
        float ei = fast_exp2(ar[0][rr] + xcur[rr * 4 + 0]);
        float ef = fast_exp2(ar[1][rr] + xcur[rr * 4 + 1]);
        float eg = fast_exp2(ar[2][rr] + xcur[rr * 4 + 2]);
        float eo = fast_exp2(ar[3][rr] + xcur[rr * 4 + 3]);
        float A = 1.f + ef, B = 1.f + ei, Cg = 1.f + eg;
        float BC = B * Cg;
        float num = cst[rr] * ef * BC + ei * (eg - 1.f) * A;
        float cn = num * fast_rcp(A * BC);
        cst[rr] = cn;
        float ec = fast_exp2(L2E2 * cn);
        float hv = eo * (ec - 1.f) * fast_rcp((1.f + eo) * (1.f + ec));
        u16 hbv = f2bf(hv);
        int row = 2 * q + rr;
        hb[(p ^ 1) * 2176 + row * 136 + hc] = hbv;
        if (LL == 0) {
          *optr[rr] = hbv;
          optr[rr] += tstep;
        }
        if (scur == TC - 1) {
          int g = (dir * 128 + wg * 8 + row) * 128 + hc;
          HS[g] = hbv;
          CS[g] = cst[rr];
          if (LL == 1 && lc == NCHUNK - 1)
            FINALS[(wg * 8 + row) * 256 + dir * 128 + hc] = hv;
        }
      }
      sync_lds();   // h-exchange: lgkmcnt(0)+barrier; VMEM stays in flight
      p ^= 1;
    }
  }
}

// ---------------------------------------------------------------------------
// fc: out[b][c] = finals[b][:] . fc_w[c][:] + fc_b[c]  (all f32)
__global__ void fc_kernel(const float* __restrict__ finals, const float* __restrict__ fcw,
                          const float* __restrict__ fcb, float* __restrict__ out) {
  int tid = threadIdx.x;  // 256 = 128 b x 2 c
  int b = tid >> 1, cc = tid & 1;
  float s = fcb[cc];
  for (int k = 0; k < 256; k++) s += finals[b * 256 + k] * fcw[cc * 256 + k];
  out[b * 2 + cc] = s;
}

// ---------------------------------------------------------------------------
extern "C" void kernel_launch(void* const* d_in, const int* in_sizes, int n_in,
                              void* d_out, int out_size, void* d_ws, size_t ws_size,
                              hipStream_t stream) {
  const int*   x        = (const int*)d_in[0];
  const float* emb      = (const float*)d_in[1];
  const float* w_ih_l0  = (const float*)d_in[2];
  const float* w_hh_l0  = (const float*)d_in[3];
  const float* b_ih_l0  = (const float*)d_in[4];
  const float* b_hh_l0  = (const float*)d_in[5];
  const float* w_ih_l0r = (const float*)d_in[6];
  const float* w_hh_l0r = (const float*)d_in[7];
  const float* b_ih_l0r = (const float*)d_in[8];
  const float* b_hh_l0r = (const float*)d_in[9];
  const float* w_ih_l1  = (const float*)d_in[10];
  const float* w_hh_l1  = (const float*)d_in[11];
  const float* b_ih_l1  = (const float*)d_in[12];
  const float* b_hh_l1  = (const float*)d_in[13];
  const float* w_ih_l1r = (const float*)d_in[14];
  const float* w_hh_l1r = (const float*)d_in[15];
  const float* b_ih_l1r = (const float*)d_in[16];
  const float* b_hh_l1r = (const float*)d_in[17];
  const float* fc_w     = (const float*)d_in[18];
  const float* fc_b     = (const float*)d_in[19];
  float* out = (float*)d_out;

  // workspace layout — total 135,856,128 B (r8-r11 footprint, proven)
  char* ws = (char*)d_ws;
  size_t off = 0;
  u16*   h1cat = (u16*)(ws + off);   off += 67108864;  // [NM][256] bf16
  u16*   xpc0  = (u16*)(ws + off);   off += 33554432;  // xp double buffer 0
  u16*   xpc1  = (u16*)(ws + off);   off += 33554432;  // xp double buffer 1
  u16*   w0pad = (u16*)(ws + off);   off += 262144;    // [2][512][128] bf16 (scaled)
  u16*   wih1b = (u16*)(ws + off);   off += 524288;    // [2][512][256] bf16 (scaled)
  u16*   whhb  = (u16*)(ws + off);   off += 524288;    // [4][512][128] bf16 (scaled)
  u16*   hs    = (u16*)(ws + off);   off += 65536;     // [2][128][128] bf16
  float* cs    = (float*)(ws + off); off += 131072;    // [2][128][128] f32
  float* fin   = (float*)(ws + off); off += 131072;    // [128][256] f32
  if (ws_size < off) return;  // constant across calls -> same work every call

  hipLaunchKernelGGL(padw_kernel, dim3(512), dim3(256), 0, stream,
                     w_ih_l0, w_ih_l0r, w0pad);
  hipLaunchKernelGGL(cvt6_kernel, dim3(512, 6), dim3(256), 0, stream,
                     w_hh_l0, w_hh_l0r, w_hh_l1, w_hh_l1r, w_ih_l1, w_ih_l1r,
                     whhb, whhb + 65536, whhb + 131072, whhb + 196608,
                     wih1b, wih1b + 131072,
                     65536, 65536, 65536, 65536, 131072, 131072);

  // Layer 0: launch k does proj0(k) [k<8] fused with lstm0(k-1) [k>0]
  for (int k = 0; k <= NCHUNK; k++) {
    int do_proj = (k < NCHUNK);
    int do_lstm = (k > 0);
    hipLaunchKernelGGL((fused_chunk<128, 0>), dim3(do_proj ? 1056 : 32), dim3(512), 0, stream,
                       do_lstm, k - 1, k,
                       emb, (const u16*)nullptr, x, w0pad, w0pad + 65536,
                       b_ih_l0, b_hh_l0, b_ih_l0r, b_hh_l0r,
                       xpc0, xpc1, whhb, whhb + 65536,
                       h1cat, fin, hs, cs);
  }
  // Layer 1: same pattern, proj reads h1cat (complete after layer-0 phase)
  for (int k = 0; k <= NCHUNK; k++) {
    int do_proj = (k < NCHUNK);
    int do_lstm = (k > 0);
    hipLaunchKernelGGL((fused_chunk<256, 1>), dim3(do_proj ? 1056 : 32), dim3(512), 0, stream,
                       do_lstm, k - 1, k,
                       (const float*)nullptr, h1cat, (const int*)nullptr,
                       wih1b, wih1b + 131072,
                       b_ih_l1, b_hh_l1, b_ih_l1r, b_hh_l1r,
                       xpc0, xpc1, whhb + 131072, whhb + 196608,
                       h1cat, fin, hs, cs);
  }
  hipLaunchKernelGGL(fc_kernel, dim3(1), dim3(256), 0, stream, fin, fc_w, fc_b, out);
}